// Round 1
// baseline (70.731 us; speedup 1.0000x reference)
//
#include <hip/hip_runtime.h>
#include <hip/hip_bf16.h>

#define DIM 8192
#define KSPLIT 16
#define PARTIAL_ELEMS (32 * DIM)   // one fp32 copy of the output per k-chunk

typedef __bf16 bf16x8 __attribute__((ext_vector_type(8)));
typedef __bf16 bf16x2 __attribute__((ext_vector_type(2)));
typedef float f32x4 __attribute__((ext_vector_type(4)));
typedef float f32x2 __attribute__((ext_vector_type(2)));

// fp32x4 -> bf16x4 (RNE, same numerics as the old bit-twiddle f2bf).
// fptrunc lets the compiler emit packed v_cvt_pk_bf16_f32 instead of 4 VALU
// ops per element.
__device__ __forceinline__ uint2 cvt_f4(const float4 v) {
  bf16x2 lo = __builtin_convertvector((f32x2){v.x, v.y}, bf16x2);
  bf16x2 hi = __builtin_convertvector((f32x2){v.z, v.w}, bf16x2);
  uint2 r;
  r.x = __builtin_bit_cast(unsigned, lo);
  r.y = __builtin_bit_cast(unsigned, hi);
  return r;
}

// grid: 512 = 32 mc (low 5 bits) x 16 kc; block 512 (8 waves).
// Occupancy bet: previous version ran 4-wave blocks -> 2 waves/SIMD (25%).
// Same total work split across 8 waves (each wave owns 2 mt values instead
// of 4) -> 4 waves/SIMD with identical LDS footprint (55.5 KB, 2 WG/CU).
// Hot loop: 16x16x32 MFMA, BOTH operand reads are wave-contiguous 1KB
// ds_read_b128 (conflict-free). Circulant trick: the two k-halves of one MFMA
// use adjacent window slots, so the blocks-fragment is the contiguous 1KB at
// slots [w0-1, w0+1).
__global__ __launch_bounds__(512, 4)
void bcl_mfma_kernel(const float* __restrict__ X,
                     const float* __restrict__ Blk,
                     float* __restrict__ Ws) {
  // x: [s:16][b0:2][kh:4][p:16][j:8] bf16 (32 KB): frag = contiguous 1KB
  __shared__ __align__(16) unsigned short Xl[16384];
  // blocks window: 47 slots x 512B, each repacked [qh:2][p:16][j:8]
  __shared__ __align__(16) unsigned short Wl[47 * 256];

  const int tid = threadIdx.x;
  const int mc  = blockIdx.x & 31;
  const int kc  = blockIdx.x >> 5;
  const int kbase = kc * 512;

  // ---- stage x (fp32->bf16). LDS stores linear (conflict-free).
  #pragma unroll
  for (int it = 0; it < 8; ++it) {
    const int L  = (tid + it * 512) << 2;     // elem index in Xl
    const int j4 = L & 7;
    const int p  = (L >> 3) & 15;
    const int kh = (L >> 7) & 3;
    const int b0 = (L >> 9) & 1;
    const int s  = (L >> 10) & 15;
    const int batch = b0 * 16 + p;
    const int kg = kbase + s * 32 + (kh >> 1) * 16 + (kh & 1) * 8 + j4;
    const float4 v = *reinterpret_cast<const float4*>(X + batch * DIM + kg);
    *reinterpret_cast<uint2*>(&Xl[L]) = cvt_f4(v);
  }

  // ---- stage blocks window: slot w holds blocks[(dbase+w)&511] as [qh][p][j]
  const int dbase = (mc * 16 - kc * 32 - 31) & 511;
  for (int i = tid; i < 47 * 64; i += 512) {
    const int w  = i >> 6;
    const int r  = (i & 63) << 2;             // elem in repacked block
    const int qh = r >> 7;
    const int p  = (r >> 3) & 15;
    const int j4 = r & 7;
    const int d  = (dbase + w) & 511;
    const float4 v = *reinterpret_cast<const float4*>(Blk + d * 256 + p * 16 + qh * 8 + j4);
    *reinterpret_cast<uint2*>(&Wl[w * 256 + r]) = cvt_f4(v);
  }

  __syncthreads();   // only barrier

  const int lane = tid & 63;
  const int wid  = tid >> 6;                  // 0..7

  // x-frag (a-operand): lane l -> Xl[s*1024 + b0*512 + l*8]
  const unsigned short* Xb = &Xl[lane << 3];
  // blocks-frag (b-operand): lanes 0-31 read slot w0, 32-63 read slot w0-1,
  // each half contiguous 512B; flat = (w0-1)*256 elems + per-lane offset:
  const unsigned short* Wb = &Wl[(((lane >> 5) ^ 1) << 8) + (((lane >> 4) & 1) << 7) + ((lane & 15) << 3)];

  f32x4 acc[2][2];
  #pragma unroll
  for (int t = 0; t < 2; ++t)
    #pragma unroll
    for (int b = 0; b < 2; ++b)
      acc[t][b] = (f32x4){0.f, 0.f, 0.f, 0.f};

  #pragma unroll 4
  for (int s = 0; s < 16; ++s) {
    const bf16x8 x0 = *reinterpret_cast<const bf16x8*>(Xb + (s << 10));
    const bf16x8 x1 = *reinterpret_cast<const bf16x8*>(Xb + (s << 10) + 512);
    #pragma unroll
    for (int t = 0; t < 2; ++t) {
      const int mt = (wid << 1) + t;          // 0..15
      const bf16x8 wf = *reinterpret_cast<const bf16x8*>(Wb + ((mt + 30 - 2 * s) << 8));
      acc[t][0] = __builtin_amdgcn_mfma_f32_16x16x32_bf16(x0, wf, acc[t][0], 0, 0, 0);
      acc[t][1] = __builtin_amdgcn_mfma_f32_16x16x32_bf16(x1, wf, acc[t][1], 0, 0, 0);
    }
  }

  // ---- epilogue: C/D 16x16 layout col=lane&15 (=p), row=(lane>>4)*4+reg (=batch-in-half)
  // each store inst: 4 rows x 16 contiguous cols (64B segments)
  float* base = Ws + (size_t)kc * PARTIAL_ELEMS + mc * 256;
  #pragma unroll
  for (int t = 0; t < 2; ++t) {
    const int col = ((wid << 1) + t) * 16 + (lane & 15);
    #pragma unroll
    for (int b0 = 0; b0 < 2; ++b0) {
      const int brow = b0 * 16 + ((lane >> 4) << 2);
      #pragma unroll
      for (int r = 0; r < 4; ++r)
        base[(brow + r) * DIM + col] = acc[t][b0][r];
    }
  }
}

// Phase 2: Out = sum of KSPLIT partials. float2 granularity -> 131072 threads
// (2 waves/SIMD, double the previous TLP for latency hiding).
__global__ __launch_bounds__(256)
void bcl_reduce_kernel(const float2* __restrict__ Ws, float2* __restrict__ Out) {
  const int f = blockIdx.x * 256 + threadIdx.x;
  float2 a = Ws[f];
  #pragma unroll
  for (int kc = 1; kc < KSPLIT; ++kc) {
    const float2 v = Ws[kc * (PARTIAL_ELEMS / 2) + f];
    a.x += v.x; a.y += v.y;
  }
  Out[f] = a;
}

extern "C" void kernel_launch(void* const* d_in, const int* in_sizes, int n_in,
                              void* d_out, int out_size, void* d_ws, size_t ws_size,
                              hipStream_t stream) {
  const float* X   = (const float*)d_in[0];   // [32, 8192] fp32
  const float* Blk = (const float*)d_in[1];   // [512, 16, 16] fp32
  float* Ws  = (float*)d_ws;                  // 16 MB partials
  float* Out = (float*)d_out;                 // [32, 8192] fp32
  bcl_mfma_kernel<<<dim3(512), dim3(512), 0, stream>>>(X, Blk, Ws);
  bcl_reduce_kernel<<<dim3(PARTIAL_ELEMS / 2 / 256), dim3(256), 0, stream>>>(
      (const float2*)Ws, (float2*)Out);
}